// Round 22
// baseline (247.372 us; speedup 1.0000x reference)
//
#include <hip/hip_runtime.h>
#include <math.h>

// Problem constants (from reference)
#define BB    2
#define SS    2048
#define HIDD  2048
#define NHH   16
#define NKVV  4
#define HDD   128
#define MROWS 4096            // B*S
#define QG_N  4096            // 2*NH*HD
#define KV_N  512             // NKV*HD
#define O_N   2048            // NH*HD
#define KDIM  2048            // shared K for all four GEMMs (row stride of A and W)
#define EPS_  1e-6f
#define SCALE_ 0.08838834764831845f   // 1/sqrt(128)
// log2(e) folded into the Q pre-scale -> softmax runs in native exp2 space
#define SCALE2_ (0.08838834764831845f * 1.4426950408889634f)
#define THR2_  11.5417f               // 8 * log2(e): same e^8 defer-max bound

typedef __attribute__((ext_vector_type(8))) __bf16 bf16x8;
typedef __attribute__((ext_vector_type(8))) unsigned short u16x8;
typedef __attribute__((ext_vector_type(4))) float f32x4;

__device__ __forceinline__ unsigned short f2bf(float f) {
  return __builtin_bit_cast(unsigned short, (__bf16)f);   // RNE via v_cvt
}
// bare v_exp_f32 (exp2) — precise exp2f without fast-math is ~6 VALU ops (r20 lesson)
__device__ __forceinline__ float fexp2(float x) {
  return __builtin_amdgcn_exp2f(x);
}

// ---------------------------------------------------------------------------
// fp32 -> bf16 convert for all four weights in ONE dispatch.
// ---------------------------------------------------------------------------
__global__ __launch_bounds__(256) void f2bf_all(const float* __restrict__ Wq,
                                                const float* __restrict__ Wk,
                                                const float* __restrict__ Wv,
                                                const float* __restrict__ Wo,
                                                unsigned short* __restrict__ dst) {
  const int s0 = QG_N * KDIM / 4;
  const int s1 = s0 + KV_N * KDIM / 4;
  const int s2 = s1 + KV_N * KDIM / 4;
  const int s3 = s2 + O_N * KDIM / 4;
  int i = blockIdx.x * 256 + threadIdx.x;
  if (i >= s3) return;
  float4 v;
  if (i < s0)      v = ((const float4*)Wq)[i];
  else if (i < s1) v = ((const float4*)Wk)[i - s0];
  else if (i < s2) v = ((const float4*)Wv)[i - s1];
  else             v = ((const float4*)Wo)[i - s2];
  ushort4 u;
  u.x = f2bf(v.x); u.y = f2bf(v.y); u.z = f2bf(v.z); u.w = f2bf(v.w);
  ((ushort4*)dst)[i] = u;
}

// ---------------------------------------------------------------------------
// RMSNorm -> bf16 x.  One block per row.
// ---------------------------------------------------------------------------
__global__ __launch_bounds__(256) void rmsnorm_k(const float* __restrict__ h,
                                                 const float* __restrict__ w,
                                                 unsigned short* __restrict__ x) {
  int row = blockIdx.x;
  int t = threadIdx.x;
  const float4* hr = (const float4*)(h + (size_t)row * HIDD);
  const float4* w4 = (const float4*)w;

  float4 v0 = hr[t], v1 = hr[t + 256];
  float ss = v0.x*v0.x + v0.y*v0.y + v0.z*v0.z + v0.w*v0.w
           + v1.x*v1.x + v1.y*v1.y + v1.z*v1.z + v1.w*v1.w;
#pragma unroll
  for (int off = 32; off > 0; off >>= 1) ss += __shfl_down(ss, off, 64);

  __shared__ float part[4];
  __shared__ float rs_sh;
  if ((t & 63) == 0) part[t >> 6] = ss;
  __syncthreads();
  if (t == 0) rs_sh = rsqrtf((part[0]+part[1]+part[2]+part[3]) * (1.0f/HIDD) + EPS_);
  __syncthreads();
  float rs = rs_sh;

  float4 w0 = w4[t], w1 = w4[t + 256];
  ushort4 o0, o1;
  o0.x = f2bf(v0.x * rs * (1.f + w0.x));
  o0.y = f2bf(v0.y * rs * (1.f + w0.y));
  o0.z = f2bf(v0.z * rs * (1.f + w0.z));
  o0.w = f2bf(v0.w * rs * (1.f + w0.w));
  o1.x = f2bf(v1.x * rs * (1.f + w1.x));
  o1.y = f2bf(v1.y * rs * (1.f + w1.y));
  o1.z = f2bf(v1.z * rs * (1.f + w1.z));
  o1.w = f2bf(v1.w * rs * (1.f + w1.w));
  ushort4* xr = (ushort4*)(x + (size_t)row * HIDD);
  xr[t] = o0;
  xr[t + 256] = o1;
}

// ---------------------------------------------------------------------------
// 128x128 bf16 MFMA GEMM core (proven path; kept for KV).
// OBF: 0 = fp32 out, 1 = bf16 out, 3 = bf16 transposed V^T[d][tok'] with the
// sigma bit-permutation folded into the token column (tok' = (tok&~63)|sig):
//   sig = (tok&32) + ((tok&12)<<1) + ((tok&16)>>2) + (tok&3)
// ---------------------------------------------------------------------------
template <int OBF>
__device__ __forceinline__ void gemm_core(const unsigned short* __restrict__ Ab,
                                          const unsigned short* __restrict__ Bb,
                                          void* __restrict__ Cv,
                                          int Ndim, int bm, int bn,
                                          unsigned short* Als, unsigned short* Bls) {
  char* ldsA = (char*)Als;
  char* ldsB = (char*)Bls;

  int t   = threadIdx.x;
  int r15 = t & 15;
  int g   = (t & 63) >> 4;
  int w   = t >> 6;
  int wr  = w >> 1, wc = w & 1;

  f32x4 acc[4][4] = {};

  for (int k0 = 0; k0 < KDIM; k0 += 64) {
    __syncthreads();
#pragma unroll
    for (int it = 0; it < 4; ++it) {
      int f      = it * 256 + t;
      int row    = f >> 3;
      int schunk = (f & 7) ^ (row & 7);
      unsigned ldsbase = (unsigned)((it * 256 + (w << 6)) << 4);
      __builtin_amdgcn_global_load_lds(
          (const unsigned int*)(Ab + ((size_t)(bm + row) << 11) + k0 + schunk * 8),
          (unsigned int*)(ldsA + ldsbase), 16, 0, 0);
      __builtin_amdgcn_global_load_lds(
          (const unsigned int*)(Bb + ((size_t)(bn + row) << 11) + k0 + schunk * 8),
          (unsigned int*)(ldsB + ldsbase), 16, 0, 0);
    }
    __syncthreads();

#pragma unroll
    for (int tt = 0; tt < 2; ++tt) {
      bf16x8 af[4], bfv[4];
#pragma unroll
      for (int mi = 0; mi < 4; ++mi) {
        int row = wr * 64 + mi * 16 + r15;
        af[mi] = *(const bf16x8*)(ldsA + row * 128 + (((4 * tt + g) ^ (row & 7)) << 4));
      }
#pragma unroll
      for (int ni = 0; ni < 4; ++ni) {
        int row = wc * 64 + ni * 16 + r15;
        bfv[ni] = *(const bf16x8*)(ldsB + row * 128 + (((4 * tt + g) ^ (row & 7)) << 4));
      }
      __builtin_amdgcn_s_setprio(1);
#pragma unroll
      for (int mi = 0; mi < 4; ++mi)
#pragma unroll
        for (int ni = 0; ni < 4; ++ni)
          acc[mi][ni] = __builtin_amdgcn_mfma_f32_16x16x32_bf16(af[mi], bfv[ni], acc[mi][ni], 0, 0, 0);
      __builtin_amdgcn_s_setprio(0);
    }
  }

#pragma unroll
  for (int mi = 0; mi < 4; ++mi)
#pragma unroll
    for (int ni = 0; ni < 4; ++ni) {
      int col = bn + wc * 64 + ni * 16 + r15;
#pragma unroll
      for (int r = 0; r < 4; ++r) {
        int rowg = bm + wr * 64 + mi * 16 + g * 4 + r;
        if (OBF == 1)
          ((unsigned short*)Cv)[(size_t)rowg * Ndim + col] = f2bf(acc[mi][ni][r]);
        else if (OBF == 3) {  // transposed bf16 V^T[d][tok'], sigma folded
          int t6 = rowg & 63;
          int sig = (t6 & 32) + ((t6 & 12) << 1) + ((t6 & 16) >> 2) + (t6 & 3);
          int tokp = (rowg & ~63) | sig;
          ((unsigned short*)Cv)[(size_t)col * MROWS + tokp] = f2bf(acc[mi][ni][r]);
        } else
          ((float*)Cv)[(size_t)rowg * Ndim + col] = acc[mi][ni][r];
      }
    }
}

template <int OBF>
__global__ __launch_bounds__(256) void gemm_bf16(const unsigned short* __restrict__ Ab,
                                                 const unsigned short* __restrict__ Bb,
                                                 void* __restrict__ Cv,
                                                 int Ndim) {
  __shared__ unsigned short Als[128 * 64];
  __shared__ unsigned short Bls[128 * 64];
  gemm_core<OBF>(Ab, Bb, Cv, Ndim, blockIdx.y * 128, blockIdx.x * 128, Als, Bls);
}

// K and V GEMMs fused; V stored TRANSPOSED + sigma-permuted (V^T[d][tok']).
__global__ __launch_bounds__(256) void gemm_kv(const unsigned short* __restrict__ Ab,
                                               const unsigned short* __restrict__ Wk,
                                               const unsigned short* __restrict__ Wv,
                                               unsigned short* __restrict__ Ck,
                                               unsigned short* __restrict__ Cvt) {
  __shared__ unsigned short Als[128 * 64];
  __shared__ unsigned short Bls[128 * 64];
  int bx = blockIdx.x;
  if (bx < 4)
    gemm_core<1>(Ab, Wk, (void*)Ck, KV_N, blockIdx.y * 128, bx * 128, Als, Bls);
  else
    gemm_core<3>(Ab, Wv, (void*)Cvt, KV_N, blockIdx.y * 128, (bx & 3) * 128, Als, Bls);
}

// ---------------------------------------------------------------------------
// QG GEMM, 256x256 8-phase counted-vmcnt schedule (r15-corrected ledger).
// ---------------------------------------------------------------------------
#define LD8(basep, r, x) \
  (*(const bf16x8*)((basep) + (size_t)(r) * 128 + ((((x) ^ ((r)&7))) << 4)))

#define STAGE_A(bufi, h, tk)                                                   \
  { _Pragma("unroll")                                                          \
    for (int c = 0; c < 2; ++c) {                                              \
      int f = c * 512 + t;                                                     \
      int rr = f >> 3;                                                         \
      int sc = (f & 7) ^ (rr & 7);                                             \
      __builtin_amdgcn_global_load_lds(                                        \
        (const unsigned int*)(Ab + ((size_t)(bm + (h)*128 + rr) << 11) + (tk)*64 + sc*8), \
        (unsigned int*)(lds8 + (bufi)*32768 + (h)*16384 + c*8192 + (w<<10)), 16, 0, 0); \
    } }

#define STAGE_B(bufi, h, tk)                                                   \
  { _Pragma("unroll")                                                          \
    for (int c = 0; c < 2; ++c) {                                              \
      int f = c * 512 + t;                                                     \
      int rr = f >> 3;                                                         \
      int sc = (f & 7) ^ (rr & 7);                                             \
      __builtin_amdgcn_global_load_lds(                                        \
        (const unsigned int*)(Bbp + ((size_t)(bn + (h)*128 + rr) << 11) + (tk)*64 + sc*8), \
        (unsigned int*)(lds8 + 65536 + (bufi)*32768 + (h)*16384 + c*8192 + (w<<10)), 16, 0, 0); \
    } }

#define RD_A(SRC, MIBASE)                                                      \
  { _Pragma("unroll")                                                          \
    for (int mi = 0; mi < 4; ++mi) {                                           \
      int rr = wr * 128 + ((MIBASE) + mi) * 16 + r15;                          \
      afr[mi][0] = LD8(SRC, rr, g);                                            \
      afr[mi][1] = LD8(SRC, rr, 4 + g);                                        \
    } }

#define RD_B(SRC, NIBASE, DST)                                                 \
  { _Pragma("unroll")                                                          \
    for (int ni = 0; ni < 2; ++ni) {                                           \
      int rr = wc * 64 + ((NIBASE) + ni) * 16 + r15;                           \
      DST[ni][0] = LD8(SRC, rr, g);                                            \
      DST[ni][1] = LD8(SRC, rr, 4 + g);                                        \
    } }

#define MFMA_QUAD(MIBASE, NIBASE, BREG)                                        \
  { __builtin_amdgcn_s_setprio(1);                                             \
    _Pragma("unroll")                                                          \
    for (int mi = 0; mi < 4; ++mi)                                             \
      _Pragma("unroll")                                                        \
      for (int ni = 0; ni < 2; ++ni)                                           \
        _Pragma("unroll")                                                      \
        for (int ks = 0; ks < 2; ++ks)                                         \
          acc[(MIBASE)+mi][(NIBASE)+ni] =                                      \
            __builtin_amdgcn_mfma_f32_16x16x32_bf16(afr[mi][ks], BREG[ni][ks], \
                                                    acc[(MIBASE)+mi][(NIBASE)+ni], 0, 0, 0); \
    __builtin_amdgcn_s_setprio(0); }

#define BAR() __builtin_amdgcn_s_barrier()

__global__ __launch_bounds__(512, 2) void gemm_qg256(const unsigned short* __restrict__ Ab,
                                                     const unsigned short* __restrict__ Bbp,
                                                     unsigned short* __restrict__ Cq,
                                                     float* __restrict__ Cg) {
  __shared__ char lds8[131072];
  int t = threadIdx.x;
  int r15 = t & 15, g = (t & 63) >> 4, w = t >> 6;
  int wr = w >> 2, wc = w & 3;
  int bm = blockIdx.y * 256, bn = blockIdx.x * 256;
  char* A0 = lds8;            char* A1 = lds8 + 32768;
  char* B0 = lds8 + 65536;    char* B1 = lds8 + 98304;

  f32x4 acc[8][4] = {};
  bf16x8 afr[4][2], b0r[2][2], b1r[2][2];

  STAGE_A(0, 0, 0); STAGE_A(0, 1, 0); STAGE_B(0, 0, 0); STAGE_B(0, 1, 0);
  STAGE_A(1, 0, 1); STAGE_A(1, 1, 1); STAGE_B(1, 0, 1); STAGE_B(1, 1, 1);
  asm volatile("s_waitcnt vmcnt(8)" ::: "memory");
  BAR();

  for (int i = 0; i < 15; ++i) {        // K-steps 0..29; te<=30, to<=31
    int te = 2 * i + 2, to = 2 * i + 3;
    RD_A(A0, 0); RD_B(B0, 0, b0r);
    BAR(); MFMA_QUAD(0, 0, b0r); BAR();
    RD_B(B0, 2, b1r);
    BAR(); MFMA_QUAD(0, 2, b1r); BAR();
    RD_A(A0, 4);
    STAGE_B(0, 0, te);
    BAR(); MFMA_QUAD(4, 0, b0r); BAR();
    STAGE_A(0, 0, te);
    BAR(); MFMA_QUAD(4, 2, b1r);
    asm volatile("s_waitcnt vmcnt(4)" ::: "memory");
    BAR();
    RD_A(A1, 0); RD_B(B1, 0, b0r);
    STAGE_A(0, 1, te);
    BAR(); MFMA_QUAD(0, 0, b0r); BAR();
    RD_B(B1, 2, b1r);
    STAGE_B(0, 1, te);
    BAR(); MFMA_QUAD(0, 2, b1r); BAR();
    RD_A(A1, 4);
    STAGE_B(1, 0, to); STAGE_B(1, 1, to);
    BAR(); MFMA_QUAD(4, 0, b0r); BAR();
    STAGE_A(1, 0, to); STAGE_A(1, 1, to);
    BAR(); MFMA_QUAD(4, 2, b1r);
    asm volatile("s_waitcnt vmcnt(8)" ::: "memory");
    BAR();
  }
  // peeled last iteration (K-steps 30,31)
  RD_A(A0, 0); RD_B(B0, 0, b0r);
  BAR(); MFMA_QUAD(0, 0, b0r); BAR();
  RD_B(B0, 2, b1r);
  BAR(); MFMA_QUAD(0, 2, b1r); BAR();
  RD_A(A0, 4);
  BAR(); MFMA_QUAD(4, 0, b0r); BAR();
  BAR(); MFMA_QUAD(4, 2, b1r);
  asm volatile("s_waitcnt vmcnt(0)" ::: "memory");
  BAR();
  RD_A(A1, 0); RD_B(B1, 0, b0r);
  BAR(); MFMA_QUAD(0, 0, b0r); BAR();
  RD_B(B1, 2, b1r);
  BAR(); MFMA_QUAD(0, 2, b1r); BAR();
  RD_A(A1, 4);
  BAR(); MFMA_QUAD(4, 0, b0r); BAR();
  BAR(); MFMA_QUAD(4, 2, b1r);

  // epilogue: q half -> bf16*(SCALE*log2e) [exp2-space softmax], gate -> fp32
  bool isq = (bn < O_N);
  int colbase = bn + wc * 64;
#pragma unroll
  for (int mi = 0; mi < 8; ++mi) {
    size_t row = (size_t)bm + wr * 128 + mi * 16 + g * 4;
#pragma unroll
    for (int ni = 0; ni < 4; ++ni) {
      int col = colbase + ni * 16 + r15;
#pragma unroll
      for (int r = 0; r < 4; ++r) {
        if (isq) Cq[(row + r) * O_N + col] = f2bf(acc[mi][ni][r] * SCALE2_);
        else     Cg[(row + r) * O_N + (col - O_N)] = acc[mi][ni][r];
      }
    }
  }
}

// ---------------------------------------------------------------------------
// O-proj GEMM v2: 256x128, 4 phases/iter, B TRIPLE-buffered (r21 post-mortem:
// v1's B was staged ph0 and read SAME-iter ph2 — a 2-phase cover tight edge
// stalling every iter at vmcnt).  New ledger (>=3-phase cover everywhere):
//   ph0: RD A0,B[te%3](n01);            stage B(te+2) -> free buf
//   ph1: RD B[te%3](n23);               stage A0h0(te+2); vmcnt(4)
//   ph2: RD A1,B[to%3](n01);            stage A0h1(te+2)+B(te+3)
//   ph3: RD B[to%3](n23);               stage A1 both(te+3); vmcnt(6)
// Steady-state invariant: 6 outstanding entering ph0 (= B(te+3)+A1(te+3)).
// Buffer indices period-3 -> outer loop 5 x 3 specialized iterations.
// LDS 112 KB: A 2x32K @0, B 3x16K @65536.
// ---------------------------------------------------------------------------
#define OST_A(bufi, h, tk)                                                     \
  { _Pragma("unroll")                                                          \
    for (int c = 0; c < 2; ++c) {                                              \
      int f = c * 512 + t;                                                     \
      int rr = f >> 3;                                                         \
      int sc = (f & 7) ^ (rr & 7);                                             \
      __builtin_amdgcn_global_load_lds(                                        \
        (const unsigned int*)(Ab + ((size_t)(bm + (h)*128 + rr) << 11) + (tk)*64 + sc*8), \
        (unsigned int*)(lds8 + (bufi)*32768 + (h)*16384 + c*8192 + (w<<10)), 16, 0, 0); \
    } }

#define OST_B3(bufi, tk)                                                       \
  { _Pragma("unroll")                                                          \
    for (int c = 0; c < 2; ++c) {                                              \
      int f = c * 512 + t;                                                     \
      int rr = f >> 3;                                                         \
      int sc = (f & 7) ^ (rr & 7);                                             \
      __builtin_amdgcn_global_load_lds(                                        \
        (const unsigned int*)(Bbp + ((size_t)(bn + rr) << 11) + (tk)*64 + sc*8), \
        (unsigned int*)(lds8 + 65536 + (bufi)*16384 + c*8192 + (w<<10)), 16, 0, 0); \
    } }

#define ORD_A(bufi)                                                            \
  { const char* abase = lds8 + (bufi)*32768 + (wr >> 1)*16384;                 \
    _Pragma("unroll")                                                          \
    for (int mi = 0; mi < 4; ++mi) {                                           \
      int rl = ((wr & 1) * 64) + mi * 16 + r15;                                \
      afr[mi][0] = LD8(abase, rl, g);                                          \
      afr[mi][1] = LD8(abase, rl, 4 + g);                                      \
    } }

#define ORD_B3(bufi, NIBASE, DST)                                              \
  { const char* bbase = lds8 + 65536 + (bufi)*16384;                           \
    _Pragma("unroll")                                                          \
    for (int ni = 0; ni < 2; ++ni) {                                           \
      int rl = wc * 64 + ((NIBASE) + ni) * 16 + r15;                           \
      DST[ni][0] = LD8(bbase, rl, g);                                          \
      DST[ni][1] = LD8(bbase, rl, 4 + g);                                      \
    } }

#define OMFMA(NIBASE, BREG)                                                    \
  { __builtin_amdgcn_s_setprio(1);                                             \
    _Pragma("unroll")                                                          \
    for (int mi = 0; mi < 4; ++mi)                                             \
      _Pragma("unroll")                                                        \
      for (int ni = 0; ni < 2; ++ni)                                           \
        _Pragma("unroll")                                                      \
        for (int ks = 0; ks < 2; ++ks)                                         \
          acc[mi][(NIBASE)+ni] =                                               \
            __builtin_amdgcn_mfma_f32_16x16x32_bf16(afr[mi][ks], BREG[ni][ks], \
                                                    acc[mi][(NIBASE)+ni], 0, 0, 0); \
    __builtin_amdgcn_s_setprio(0); }

// One iteration; BTE/BTO/BS0/BS1 are literal buffer indices:
// BTE = te%3, BTO = (te+1)%3, BS0 = (te+2)%3 (free buf), BS1 = (te+3)%3 (=BTE)
#define OITER(TE, BTE, BTO, BS0, BS1)                                          \
  {                                                                            \
    int te2 = (TE) + 2, te3 = (TE) + 3;                                        \
    ORD_A(0); ORD_B3(BTE, 0, b0r);                                             \
    OST_B3(BS0, te2);                                                          \
    BAR(); OMFMA(0, b0r); BAR();                                               \
    ORD_B3(BTE, 2, b1r);                                                       \
    OST_A(0, 0, te2);                                                          \
    BAR(); OMFMA(2, b1r);                                                      \
    asm volatile("s_waitcnt vmcnt(4)" ::: "memory");                           \
    BAR();                                                                     \
    ORD_A(1); ORD_B3(BTO, 0, b0r);                                             \
    OST_A(0, 1, te2); OST_B3(BS1, te3);                                        \
    BAR(); OMFMA(0, b0r); BAR();                                               \
    ORD_B3(BTO, 2, b1r);                                                       \
    OST_A(1, 0, te3); OST_A(1, 1, te3);                                        \
    BAR(); OMFMA(2, b1r);                                                      \
    asm volatile("s_waitcnt vmcnt(6)" ::: "memory");                           \
    BAR();                                                                     \
  }

__global__ __launch_bounds__(512, 2) void gemm_o256(const unsigned short* __restrict__ Ab,
                                                    const unsigned short* __restrict__ Bbp,
                                                    float* __restrict__ C) {
  __shared__ char lds8[114688];
  int t = threadIdx.x;
  int r15 = t & 15, g = (t & 63) >> 4, w = t >> 6;
  int wr = w >> 1, wc = w & 1;
  int bm = blockIdx.y * 256, bn = blockIdx.x * 128;

  f32x4 acc[4][4] = {};
  bf16x8 afr[4][2], b0r[2][2], b1r[2][2];

  // prologue: B(0)->buf0, A0(0), B(1)->buf1, A1(1).  Wait first 6 (B0+A0).
  OST_B3(0, 0);
  OST_A(0, 0, 0); OST_A(0, 1, 0);
  OST_B3(1, 1);
  OST_A(1, 0, 1); OST_A(1, 1, 1);
  asm volatile("s_waitcnt vmcnt(6)" ::: "memory");
  BAR();

  // 15 iterations = 5 x 3 (buffer indices period 3 in te=2i: 0,2,1,0,2,1,...)
  for (int ii = 0; ii < 5; ++ii) {
    int teb = 6 * ii;
    OITER(teb,     0, 1, 2, 0);   // te%3=0, to%3=1, S0=2, S1=0
    OITER(teb + 2, 2, 0, 1, 2);   // te%3=2, to%3=0, S0=1, S1=2
    OITER(teb + 4, 1, 2, 0, 1);   // te%3=1, to%3=2, S0=0, S1=1
  }
  // peel: K-steps 30 (buf 30%3=0) and 31 (buf 31%3=1); no stages
  ORD_A(0); ORD_B3(0, 0, b0r);
  BAR(); OMFMA(0, b0r); BAR();
  ORD_B3(0, 2, b1r);
  BAR(); OMFMA(2, b1r);
  asm volatile("s_waitcnt vmcnt(0)" ::: "memory");   // drain B(31)+A1(31)
  BAR();
  ORD_A(1); ORD_B3(1, 0, b0r);
  BAR(); OMFMA(0, b0r); BAR();
  ORD_B3(1, 2, b1r);
  BAR(); OMFMA(2, b1r);

  // epilogue: fp32 store
#pragma unroll
  for (int mi = 0; mi < 4; ++mi) {
    size_t row = (size_t)bm + wr * 64 + mi * 16 + g * 4;
#pragma unroll
    for (int ni = 0; ni < 4; ++ni) {
      int col = bn + wc * 64 + ni * 16 + r15;
#pragma unroll
      for (int r = 0; r < 4; ++r)
        C[(row + r) * O_N + col] = acc[mi][ni][r];
    }
  }
}

// ---------------------------------------------------------------------------
// bf16 MFMA flash attention v10 (unchanged from r21 — 89.6 us best).
// ---------------------------------------------------------------------------
__global__ __launch_bounds__(256, 2) void attn_mfma(const unsigned short* __restrict__ qb,
                                                    const float* __restrict__ gateb,
                                                    const unsigned short* __restrict__ kb,
                                                    const unsigned short* __restrict__ vt,
                                                    unsigned short* __restrict__ obuf) {
  __shared__ unsigned short Ks[2][64 * 128];   // [kv][d], chunk^=(kv&7) swizzle
  __shared__ unsigned short Vt[2][128 * 64];   // [d][sig(tok)], chunk^=(d&7) swizzle
  char* ldsK0 = (char*)Ks;
  char* ldsV0 = (char*)Vt;

  int t = threadIdx.x;
  int l = t & 63, w = t >> 6;
  int c15 = l & 15, g = l >> 4;
  int bid = blockIdx.x;
  int swz = (bid & 7) * 64 + (bid >> 3);
  int qt = swz & 15, h = (swz >> 4) & 15, b = swz >> 8;
  int kh = h >> 2;                          // G = 4
  size_t rowQ0 = (size_t)b * SS + (size_t)qt * 128;
  size_t rowKbase = (size_t)b * SS;

  bf16x8 qf[2][4];
#pragma unroll
  for (int qi = 0; qi < 2; ++qi)
#pragma unroll
    for (int ks = 0; ks < 4; ++ks)
      qf[qi][ks] = *(const bf16x8*)(qb + (rowQ0 + w * 32 + qi * 16 + c15) * O_N
                                       + h * HDD + g * 8 + ks * 32);

  f32x4 accO[2][8] = {};
  float mrun[2] = {-INFINITY, -INFINITY};
  float lrun[2] = {0.f, 0.f};

#define ISSUE_K(bufi, kt_)                                                     \
  {                                                                            \
    size_t rowK0 = rowKbase + (size_t)(kt_) * 64;                              \
    _Pragma("unroll")                                                          \
    for (int it = 0; it < 4; ++it) {                                           \
      int f = it * 256 + t;                                                    \
      int kv = f >> 4;                                                         \
      int schunk = (f & 15) ^ (kv & 7);                                        \
      unsigned ldsbase = (unsigned)((it * 256 + (w << 6)) << 4);               \
      __builtin_amdgcn_global_load_lds(                                        \
          (const unsigned int*)(kb + (rowK0 + kv) * KV_N + kh * HDD + schunk * 8), \
          (unsigned int*)(ldsK0 + (bufi) * 16384 + ldsbase), 16, 0, 0);        \
    }                                                                          \
  }
#define ISSUE_VT(bufi, kt_)                                                    \
  {                                                                            \
    size_t tokbase = rowKbase + (size_t)(kt_) * 64;                            \
    _Pragma("unroll")                                                          \
    for (int it = 0; it < 4; ++it) {                                           \
      int f = it * 256 + t;                                                    \
      int row = f >> 3;                                                        \
      int schunk = (f & 7) ^ (row & 7);                                        \
      unsigned ldsbase = (unsigned)((it * 256 + (w << 6)) << 4);               \
      __builtin_amdgcn_global_load_lds(                                        \
          (const unsigned int*)(vt + (size_t)(kh * 128 + row) * MROWS + tokbase + schunk * 8), \
          (unsigned int*)(ldsV0 + (bufi) * 16384 + ldsbase), 16, 0, 0);        \
    }                                                                          \
  }

  ISSUE_K(0, 0);
  ISSUE_VT(0, 0);
  asm volatile("s_waitcnt vmcnt(0)" ::: "memory");
  __syncthreads();

  const int NT = SS / 64;
  for (int kt = 0; kt < NT; ++kt) {
    int cur = kt & 1, nxt = cur ^ 1;
    char* ldsK = ldsK0 + cur * 16384;
    char* ldsV = ldsV0 + cur * 16384;

    if (kt + 1 < NT) {
      ISSUE_K(nxt, kt + 1);
      ISSUE_VT(nxt, kt + 1);
    }

    f32x4 accS[2][4] = {};
    __builtin_amdgcn_s_setprio(1);
#pragma unroll
    for (int nf = 0; nf < 4; ++nf) {
      int kvr = nf * 16 + c15;
#pragma unroll
      for (int ks = 0; ks < 4; ++ks) {
        bf16x8 kf = *(const bf16x8*)(ldsK + kvr * 256 + ((((g + 4 * ks) ^ (kvr & 7)) << 4)));
#pragma unroll
        for (int qi = 0; qi < 2; ++qi)
          accS[qi][nf] = __builtin_amdgcn_mfma_f32_16x16x32_bf16(kf, qf[qi][ks], accS[qi][nf], 0, 0, 0);
      }
    }
    __builtin_amdgcn_s_setprio(0);

    float mt[2];
#pragma unroll
    for (int qi = 0; qi < 2; ++qi) {
      float m0 = fmaxf(fmaxf(accS[qi][0][0], accS[qi][0][1]), fmaxf(accS[qi][0][2], accS[qi][0][3]));
#pragma unroll
      for (int nf = 1; nf < 4; ++nf)
        m0 = fmaxf(m0, fmaxf(fmaxf(accS[qi][nf][0], accS[qi][nf][1]), fmaxf(accS[qi][nf][2], accS[qi][nf][3])));
      m0 = fmaxf(m0, __shfl_xor(m0, 16, 64));
      m0 = fmaxf(m0, __shfl_xor(m0, 32, 64));
      mt[qi] = m0;
    }

    // defer-max (exp2 space): skip rescale when bounded by 2^THR2 = e^8
    bool safe = (mt[0] <= mrun[0] + THR2_) && (mt[1] <= mrun[1] + THR2_);
    if (!__all(safe)) {
#pragma unroll
      for (int qi = 0; qi < 2; ++qi) {
        float mnew = fmaxf(mrun[qi], mt[qi]);
        float al = fexp2(mrun[qi] - mnew);    // first tile: exp2(-inf)=0
        mrun[qi] = mnew;
        lrun[qi] *= al;
        float alr[4];
#pragma unroll
        for (int r = 0; r < 4; ++r) alr[r] = __shfl(al, g * 4 + r, 16);
#pragma unroll
        for (int df = 0; df < 8; ++df)
#pragma unroll
          for (int r = 0; r < 4; ++r) accO[qi][df][r] *= alr[r];
      }
    }

    u16x8 pfr[2][2];
#pragma unroll
    for (int qi = 0; qi < 2; ++qi) {
      float ps = 0.f;
#pragma unroll
      for (int nf = 0; nf < 4; ++nf) {
        float p0 = fexp2(accS[qi][nf][0] - mrun[qi]);
        float p1 = fexp2(accS[qi][nf][1] - mrun[qi]);
        float p2 = fexp2(accS[qi][nf][2] - mrun[qi]);
        float p3 = fexp2(accS[qi][nf][3] - mrun[qi]);
        ps += (p0 + p1) + (p2 + p3);
        pfr[qi][nf >> 1][(nf & 1) * 4 + 0] = f2bf(p0);
        pfr[qi][nf >> 1][(nf & 1) * 4 + 1] = f2bf(p1);
        pfr[qi][nf >> 1][(nf & 1) * 4 + 2] = f2bf(p2);
        pfr[qi][nf >> 1][(nf & 1) * 4 + 3] = f2bf(p3);
      }
      lrun[qi] += ps;               // per-lane partial; cross-lane in epilogue
    }

    // O += P V : 32 MFMA.  A = pfr (own regs), B = ONE b128 from sigma-space Vt
    __builtin_amdgcn_s_setprio(1);
#pragma unroll
    for (int ks2 = 0; ks2 < 2; ++ks2) {
      bf16x8 pf0 = __builtin_bit_cast(bf16x8, pfr[0][ks2]);
      bf16x8 pf1 = __builtin_bit_cast(bf16x8, pfr[1][ks2]);
#pragma unroll
      for (int df = 0; df < 8; ++df) {
        int d = df * 16 + c15;
        bf16x8 vf = *(const bf16x8*)(ldsV + d * 128 + ((((g + 4 * ks2) ^ (d & 7)) << 4)));
        accO[0][df] = __builtin_amdgcn_mfma_f32_16x16x32_bf16(pf0, vf, accO[0][df], 0, 0, 0);
        accO[1][df] = __builtin_amdgcn_mfma_f32_16x16x32_bf16(pf1, vf, accO[1][df], 0, 0, 0);
      }
    }
    __builtin_amdgcn_s_setprio(0);

    if (kt + 1 < NT) {
      asm volatile("s_waitcnt vmcnt(0)" ::: "memory");
    }
    __syncthreads();
  }

  // epilogue: finish lrun reduce, normalize, sigmoid-gate, bf16 store
#pragma unroll
  for (int qi = 0; qi < 2; ++qi) {
    lrun[qi] += __shfl_xor(lrun[qi], 16, 64);
    lrun[qi] += __shfl_xor(lrun[qi], 32, 64);
    float invL = 1.f / lrun[qi];
    float ivr[4];
#pragma unroll
    for (int r = 0; r < 4; ++r) ivr[r] = __shfl(invL, g * 4 + r, 16);
#pragma unroll
    for (int r = 0; r < 4; ++r) {
      size_t row = rowQ0 + w * 32 + qi * 16 + g * 4 + r;
#pragma unroll
      for (int df = 0; df < 8; ++df) {
        int d = df * 16 + c15;
        float gt = gateb[row * (size_t)O_N + h * HDD + d];
        float sg = 1.f / (1.f + __expf(-gt));
        obuf[row * (size_t)O_N + h * HDD + d] = f2bf(accO[qi][df][r] * ivr[r] * sg);
      }
    }
  }
#undef ISSUE_K
#undef ISSUE_VT
}

// ---------------------------------------------------------------------------
// Launch
// ---------------------------------------------------------------------------
extern "C" void kernel_launch(void* const* d_in, const int* in_sizes, int n_in,
                              void* d_out, int out_size, void* d_ws, size_t ws_size,
                              hipStream_t stream) {
  const float* hs = (const float*)d_in[0];
  // d_in[1] = position_ids (unused by the reference)
  const float* Wq = (const float*)d_in[2];
  const float* Wk = (const float*)d_in[3];
  const float* Wv = (const float*)d_in[4];
  const float* Wo = (const float*)d_in[5];
  const float* nw = (const float*)d_in[6];
  float* out = (float*)d_out;

  // workspace (~121 MB): gate fp32 | bf16: qb,kb,vt,x,ob | bf16 W (contiguous)
  float* gateb = (float*)d_ws;
  unsigned short* qb16 = (unsigned short*)(gateb + (size_t)MROWS * O_N);
  unsigned short* kb16 = qb16 + (size_t)MROWS * O_N;
  unsigned short* vt16 = kb16 + (size_t)MROWS * KV_N;   // V^T [512][4096], sigma-permuted
  unsigned short* xb   = vt16 + (size_t)KV_N * MROWS;
  unsigned short* ob   = xb   + (size_t)MROWS * HIDD;
  unsigned short* wqb  = ob   + (size_t)MROWS * O_N;
  unsigned short* wkb  = wqb  + (size_t)QG_N * KDIM;
  unsigned short* wvb  = wkb  + (size_t)KV_N * KDIM;
  unsigned short* wob  = wvb  + (size_t)KV_N * KDIM;

  const int tot4 = (QG_N + KV_N + KV_N + O_N) * KDIM / 4;
  f2bf_all<<<(tot4 + 255) / 256, 256, 0, stream>>>(Wq, Wk, Wv, Wo, wqb);
  rmsnorm_k<<<MROWS, 256, 0, stream>>>(hs, nw, xb);

  gemm_qg256<<<dim3(QG_N/256, MROWS/256), 512, 0, stream>>>(xb, wqb, qb16, gateb);
  gemm_kv<<<dim3(8, MROWS/128), 256, 0, stream>>>(xb, wkb, wvb, kb16, vt16);
  attn_mfma<<<dim3(512), 256, 0, stream>>>(qb16, gateb, kb16, vt16, ob);
  gemm_o256<<<dim3(O_N/128, MROWS/256), 512, 0, stream>>>(ob, wob, out);
}

// Round 23
// 245.022 us; speedup vs baseline: 1.0096x; 1.0096x over previous
//
#include <hip/hip_runtime.h>
#include <math.h>

// Problem constants (from reference)
#define BB    2
#define SS    2048
#define HIDD  2048
#define NHH   16
#define NKVV  4
#define HDD   128
#define MROWS 4096            // B*S
#define QG_N  4096            // 2*NH*HD
#define KV_N  512             // NKV*HD
#define O_N   2048            // NH*HD
#define KDIM  2048            // shared K for all four GEMMs (row stride of A and W)
#define EPS_  1e-6f
#define SCALE_ 0.08838834764831845f   // 1/sqrt(128)
// log2(e) folded into the Q pre-scale -> softmax runs in native exp2 space
#define SCALE2_ (0.08838834764831845f * 1.4426950408889634f)
#define THR2_  11.5417f               // 8 * log2(e): same e^8 defer-max bound
#define NWBLK 14336                   // weight-convert blocks in fused prep

typedef __attribute__((ext_vector_type(8))) __bf16 bf16x8;
typedef __attribute__((ext_vector_type(8))) unsigned short u16x8;
typedef __attribute__((ext_vector_type(4))) float f32x4;

__device__ __forceinline__ unsigned short f2bf(float f) {
  return __builtin_bit_cast(unsigned short, (__bf16)f);   // RNE via v_cvt
}
// bare v_exp_f32 (exp2) — precise exp2f without fast-math is ~6 VALU ops (r20 lesson)
__device__ __forceinline__ float fexp2(float x) {
  return __builtin_amdgcn_exp2f(x);
}

// ---------------------------------------------------------------------------
// Fused prep: blocks [0,NWBLK) convert all four weights fp32->bf16 into the
// contiguous wdst region; blocks [NWBLK, NWBLK+MROWS) do RMSNorm -> bf16 x.
// Math byte-identical to the former two dispatches.
// ---------------------------------------------------------------------------
__global__ __launch_bounds__(256) void prep_k(const float* __restrict__ Wq,
                                              const float* __restrict__ Wk,
                                              const float* __restrict__ Wv,
                                              const float* __restrict__ Wo,
                                              const float* __restrict__ hs,
                                              const float* __restrict__ nw,
                                              unsigned short* __restrict__ wdst,
                                              unsigned short* __restrict__ x) {
  if (blockIdx.x < NWBLK) {
    const int s0 = QG_N * KDIM / 4;
    const int s1 = s0 + KV_N * KDIM / 4;
    const int s2 = s1 + KV_N * KDIM / 4;
    int i = blockIdx.x * 256 + threadIdx.x;
    float4 v;
    if (i < s0)      v = ((const float4*)Wq)[i];
    else if (i < s1) v = ((const float4*)Wk)[i - s0];
    else if (i < s2) v = ((const float4*)Wv)[i - s1];
    else             v = ((const float4*)Wo)[i - s2];
    ushort4 u;
    u.x = f2bf(v.x); u.y = f2bf(v.y); u.z = f2bf(v.z); u.w = f2bf(v.w);
    ((ushort4*)wdst)[i] = u;
    return;
  }
  // RMSNorm path
  int row = blockIdx.x - NWBLK;
  int t = threadIdx.x;
  const float4* hr = (const float4*)(hs + (size_t)row * HIDD);
  const float4* w4 = (const float4*)nw;

  float4 v0 = hr[t], v1 = hr[t + 256];
  float ss = v0.x*v0.x + v0.y*v0.y + v0.z*v0.z + v0.w*v0.w
           + v1.x*v1.x + v1.y*v1.y + v1.z*v1.z + v1.w*v1.w;
#pragma unroll
  for (int off = 32; off > 0; off >>= 1) ss += __shfl_down(ss, off, 64);

  __shared__ float part[4];
  __shared__ float rs_sh;
  if ((t & 63) == 0) part[t >> 6] = ss;
  __syncthreads();
  if (t == 0) rs_sh = rsqrtf((part[0]+part[1]+part[2]+part[3]) * (1.0f/HIDD) + EPS_);
  __syncthreads();
  float rs = rs_sh;

  float4 w0 = w4[t], w1 = w4[t + 256];
  ushort4 o0, o1;
  o0.x = f2bf(v0.x * rs * (1.f + w0.x));
  o0.y = f2bf(v0.y * rs * (1.f + w0.y));
  o0.z = f2bf(v0.z * rs * (1.f + w0.z));
  o0.w = f2bf(v0.w * rs * (1.f + w0.w));
  o1.x = f2bf(v1.x * rs * (1.f + w1.x));
  o1.y = f2bf(v1.y * rs * (1.f + w1.y));
  o1.z = f2bf(v1.z * rs * (1.f + w1.z));
  o1.w = f2bf(v1.w * rs * (1.f + w1.w));
  ushort4* xr = (ushort4*)(x + (size_t)row * HIDD);
  xr[t] = o0;
  xr[t + 256] = o1;
}

// ---------------------------------------------------------------------------
// 128x128 bf16 MFMA GEMM core (proven path; kept for KV).
// OBF: 1 = bf16 out, 3 = bf16 transposed V^T[d][tok'] with the sigma
// bit-permutation folded into the token column (tok' = (tok&~63)|sig):
//   sig = (tok&32) + ((tok&12)<<1) + ((tok&16)>>2) + (tok&3)
// ---------------------------------------------------------------------------
template <int OBF>
__device__ __forceinline__ void gemm_core(const unsigned short* __restrict__ Ab,
                                          const unsigned short* __restrict__ Bb,
                                          void* __restrict__ Cv,
                                          int Ndim, int bm, int bn,
                                          unsigned short* Als, unsigned short* Bls) {
  char* ldsA = (char*)Als;
  char* ldsB = (char*)Bls;

  int t   = threadIdx.x;
  int r15 = t & 15;
  int g   = (t & 63) >> 4;
  int w   = t >> 6;
  int wr  = w >> 1, wc = w & 1;

  f32x4 acc[4][4] = {};

  for (int k0 = 0; k0 < KDIM; k0 += 64) {
    __syncthreads();
#pragma unroll
    for (int it = 0; it < 4; ++it) {
      int f      = it * 256 + t;
      int row    = f >> 3;
      int schunk = (f & 7) ^ (row & 7);
      unsigned ldsbase = (unsigned)((it * 256 + (w << 6)) << 4);
      __builtin_amdgcn_global_load_lds(
          (const unsigned int*)(Ab + ((size_t)(bm + row) << 11) + k0 + schunk * 8),
          (unsigned int*)(ldsA + ldsbase), 16, 0, 0);
      __builtin_amdgcn_global_load_lds(
          (const unsigned int*)(Bb + ((size_t)(bn + row) << 11) + k0 + schunk * 8),
          (unsigned int*)(ldsB + ldsbase), 16, 0, 0);
    }
    __syncthreads();

#pragma unroll
    for (int tt = 0; tt < 2; ++tt) {
      bf16x8 af[4], bfv[4];
#pragma unroll
      for (int mi = 0; mi < 4; ++mi) {
        int row = wr * 64 + mi * 16 + r15;
        af[mi] = *(const bf16x8*)(ldsA + row * 128 + (((4 * tt + g) ^ (row & 7)) << 4));
      }
#pragma unroll
      for (int ni = 0; ni < 4; ++ni) {
        int row = wc * 64 + ni * 16 + r15;
        bfv[ni] = *(const bf16x8*)(ldsB + row * 128 + (((4 * tt + g) ^ (row & 7)) << 4));
      }
      __builtin_amdgcn_s_setprio(1);
#pragma unroll
      for (int mi = 0; mi < 4; ++mi)
#pragma unroll
        for (int ni = 0; ni < 4; ++ni)
          acc[mi][ni] = __builtin_amdgcn_mfma_f32_16x16x32_bf16(af[mi], bfv[ni], acc[mi][ni], 0, 0, 0);
      __builtin_amdgcn_s_setprio(0);
    }
  }

#pragma unroll
  for (int mi = 0; mi < 4; ++mi)
#pragma unroll
    for (int ni = 0; ni < 4; ++ni) {
      int col = bn + wc * 64 + ni * 16 + r15;
#pragma unroll
      for (int r = 0; r < 4; ++r) {
        int rowg = bm + wr * 64 + mi * 16 + g * 4 + r;
        if (OBF == 1)
          ((unsigned short*)Cv)[(size_t)rowg * Ndim + col] = f2bf(acc[mi][ni][r]);
        else if (OBF == 3) {  // transposed bf16 V^T[d][tok'], sigma folded
          int t6 = rowg & 63;
          int sig = (t6 & 32) + ((t6 & 12) << 1) + ((t6 & 16) >> 2) + (t6 & 3);
          int tokp = (rowg & ~63) | sig;
          ((unsigned short*)Cv)[(size_t)col * MROWS + tokp] = f2bf(acc[mi][ni][r]);
        } else
          ((float*)Cv)[(size_t)rowg * Ndim + col] = acc[mi][ni][r];
      }
    }
}

// K and V GEMMs fused; V stored TRANSPOSED + sigma-permuted (V^T[d][tok']).
__global__ __launch_bounds__(256) void gemm_kv(const unsigned short* __restrict__ Ab,
                                               const unsigned short* __restrict__ Wk,
                                               const unsigned short* __restrict__ Wv,
                                               unsigned short* __restrict__ Ck,
                                               unsigned short* __restrict__ Cvt) {
  __shared__ unsigned short Als[128 * 64];
  __shared__ unsigned short Bls[128 * 64];
  int bx = blockIdx.x;
  if (bx < 4)
    gemm_core<1>(Ab, Wk, (void*)Ck, KV_N, blockIdx.y * 128, bx * 128, Als, Bls);
  else
    gemm_core<3>(Ab, Wv, (void*)Cvt, KV_N, blockIdx.y * 128, (bx & 3) * 128, Als, Bls);
}

// ---------------------------------------------------------------------------
// QG GEMM, 256x256 8-phase counted-vmcnt schedule (r15-corrected ledger).
// ---------------------------------------------------------------------------
#define LD8(basep, r, x) \
  (*(const bf16x8*)((basep) + (size_t)(r) * 128 + ((((x) ^ ((r)&7))) << 4)))

#define STAGE_A(bufi, h, tk)                                                   \
  { _Pragma("unroll")                                                          \
    for (int c = 0; c < 2; ++c) {                                              \
      int f = c * 512 + t;                                                     \
      int rr = f >> 3;                                                         \
      int sc = (f & 7) ^ (rr & 7);                                             \
      __builtin_amdgcn_global_load_lds(                                        \
        (const unsigned int*)(Ab + ((size_t)(bm + (h)*128 + rr) << 11) + (tk)*64 + sc*8), \
        (unsigned int*)(lds8 + (bufi)*32768 + (h)*16384 + c*8192 + (w<<10)), 16, 0, 0); \
    } }

#define STAGE_B(bufi, h, tk)                                                   \
  { _Pragma("unroll")                                                          \
    for (int c = 0; c < 2; ++c) {                                              \
      int f = c * 512 + t;                                                     \
      int rr = f >> 3;                                                         \
      int sc = (f & 7) ^ (rr & 7);                                             \
      __builtin_amdgcn_global_load_lds(                                        \
        (const unsigned int*)(Bbp + ((size_t)(bn + (h)*128 + rr) << 11) + (tk)*64 + sc*8), \
        (unsigned int*)(lds8 + 65536 + (bufi)*32768 + (h)*16384 + c*8192 + (w<<10)), 16, 0, 0); \
    } }

#define RD_A(SRC, MIBASE)                                                      \
  { _Pragma("unroll")                                                          \
    for (int mi = 0; mi < 4; ++mi) {                                           \
      int rr = wr * 128 + ((MIBASE) + mi) * 16 + r15;                          \
      afr[mi][0] = LD8(SRC, rr, g);                                            \
      afr[mi][1] = LD8(SRC, rr, 4 + g);                                        \
    } }

#define RD_B(SRC, NIBASE, DST)                                                 \
  { _Pragma("unroll")                                                          \
    for (int ni = 0; ni < 2; ++ni) {                                           \
      int rr = wc * 64 + ((NIBASE) + ni) * 16 + r15;                           \
      DST[ni][0] = LD8(SRC, rr, g);                                            \
      DST[ni][1] = LD8(SRC, rr, 4 + g);                                        \
    } }

#define MFMA_QUAD(MIBASE, NIBASE, BREG)                                        \
  { __builtin_amdgcn_s_setprio(1);                                             \
    _Pragma("unroll")                                                          \
    for (int mi = 0; mi < 4; ++mi)                                             \
      _Pragma("unroll")                                                        \
      for (int ni = 0; ni < 2; ++ni)                                           \
        _Pragma("unroll")                                                      \
        for (int ks = 0; ks < 2; ++ks)                                         \
          acc[(MIBASE)+mi][(NIBASE)+ni] =                                      \
            __builtin_amdgcn_mfma_f32_16x16x32_bf16(afr[mi][ks], BREG[ni][ks], \
                                                    acc[(MIBASE)+mi][(NIBASE)+ni], 0, 0, 0); \
    __builtin_amdgcn_s_setprio(0); }

#define BAR() __builtin_amdgcn_s_barrier()

__global__ __launch_bounds__(512, 2) void gemm_qg256(const unsigned short* __restrict__ Ab,
                                                     const unsigned short* __restrict__ Bbp,
                                                     unsigned short* __restrict__ Cq,
                                                     float* __restrict__ Cg) {
  __shared__ char lds8[131072];
  int t = threadIdx.x;
  int r15 = t & 15, g = (t & 63) >> 4, w = t >> 6;
  int wr = w >> 2, wc = w & 3;
  int bm = blockIdx.y * 256, bn = blockIdx.x * 256;
  char* A0 = lds8;            char* A1 = lds8 + 32768;
  char* B0 = lds8 + 65536;    char* B1 = lds8 + 98304;

  f32x4 acc[8][4] = {};
  bf16x8 afr[4][2], b0r[2][2], b1r[2][2];

  STAGE_A(0, 0, 0); STAGE_A(0, 1, 0); STAGE_B(0, 0, 0); STAGE_B(0, 1, 0);
  STAGE_A(1, 0, 1); STAGE_A(1, 1, 1); STAGE_B(1, 0, 1); STAGE_B(1, 1, 1);
  asm volatile("s_waitcnt vmcnt(8)" ::: "memory");
  BAR();

  for (int i = 0; i < 15; ++i) {        // K-steps 0..29; te<=30, to<=31
    int te = 2 * i + 2, to = 2 * i + 3;
    RD_A(A0, 0); RD_B(B0, 0, b0r);
    BAR(); MFMA_QUAD(0, 0, b0r); BAR();
    RD_B(B0, 2, b1r);
    BAR(); MFMA_QUAD(0, 2, b1r); BAR();
    RD_A(A0, 4);
    STAGE_B(0, 0, te);
    BAR(); MFMA_QUAD(4, 0, b0r); BAR();
    STAGE_A(0, 0, te);
    BAR(); MFMA_QUAD(4, 2, b1r);
    asm volatile("s_waitcnt vmcnt(4)" ::: "memory");
    BAR();
    RD_A(A1, 0); RD_B(B1, 0, b0r);
    STAGE_A(0, 1, te);
    BAR(); MFMA_QUAD(0, 0, b0r); BAR();
    RD_B(B1, 2, b1r);
    STAGE_B(0, 1, te);
    BAR(); MFMA_QUAD(0, 2, b1r); BAR();
    RD_A(A1, 4);
    STAGE_B(1, 0, to); STAGE_B(1, 1, to);
    BAR(); MFMA_QUAD(4, 0, b0r); BAR();
    STAGE_A(1, 0, to); STAGE_A(1, 1, to);
    BAR(); MFMA_QUAD(4, 2, b1r);
    asm volatile("s_waitcnt vmcnt(8)" ::: "memory");
    BAR();
  }
  // peeled last iteration (K-steps 30,31)
  RD_A(A0, 0); RD_B(B0, 0, b0r);
  BAR(); MFMA_QUAD(0, 0, b0r); BAR();
  RD_B(B0, 2, b1r);
  BAR(); MFMA_QUAD(0, 2, b1r); BAR();
  RD_A(A0, 4);
  BAR(); MFMA_QUAD(4, 0, b0r); BAR();
  BAR(); MFMA_QUAD(4, 2, b1r);
  asm volatile("s_waitcnt vmcnt(0)" ::: "memory");
  BAR();
  RD_A(A1, 0); RD_B(B1, 0, b0r);
  BAR(); MFMA_QUAD(0, 0, b0r); BAR();
  RD_B(B1, 2, b1r);
  BAR(); MFMA_QUAD(0, 2, b1r); BAR();
  RD_A(A1, 4);
  BAR(); MFMA_QUAD(4, 0, b0r); BAR();
  BAR(); MFMA_QUAD(4, 2, b1r);

  // epilogue: q half -> bf16*(SCALE*log2e) [exp2-space softmax], gate -> fp32
  bool isq = (bn < O_N);
  int colbase = bn + wc * 64;
#pragma unroll
  for (int mi = 0; mi < 8; ++mi) {
    size_t row = (size_t)bm + wr * 128 + mi * 16 + g * 4;
#pragma unroll
    for (int ni = 0; ni < 4; ++ni) {
      int col = colbase + ni * 16 + r15;
#pragma unroll
      for (int r = 0; r < 4; ++r) {
        if (isq) Cq[(row + r) * O_N + col] = f2bf(acc[mi][ni][r] * SCALE2_);
        else     Cg[(row + r) * O_N + (col - O_N)] = acc[mi][ni][r];
      }
    }
  }
}

// ---------------------------------------------------------------------------
// O-proj GEMM, 256x128 8-phase counted-vmcnt schedule (r17/r21 ledger —
// double-buffered B; the r22 triple-buffer was neutral and is reverted).
// ---------------------------------------------------------------------------
#define OST_A(bufi, h, tk)                                                     \
  { _Pragma("unroll")                                                          \
    for (int c = 0; c < 2; ++c) {                                              \
      int f = c * 512 + t;                                                     \
      int rr = f >> 3;                                                         \
      int sc = (f & 7) ^ (rr & 7);                                             \
      __builtin_amdgcn_global_load_lds(                                        \
        (const unsigned int*)(Ab + ((size_t)(bm + (h)*128 + rr) << 11) + (tk)*64 + sc*8), \
        (unsigned int*)(lds8 + (bufi)*32768 + (h)*16384 + c*8192 + (w<<10)), 16, 0, 0); \
    } }

#define OST_B(bufi, tk)                                                        \
  { _Pragma("unroll")                                                          \
    for (int c = 0; c < 2; ++c) {                                              \
      int f = c * 512 + t;                                                     \
      int rr = f >> 3;                                                         \
      int sc = (f & 7) ^ (rr & 7);                                             \
      __builtin_amdgcn_global_load_lds(                                        \
        (const unsigned int*)(Bbp + ((size_t)(bn + rr) << 11) + (tk)*64 + sc*8), \
        (unsigned int*)(lds8 + 65536 + (bufi)*16384 + c*8192 + (w<<10)), 16, 0, 0); \
    } }

#define ORD_A(bufi)                                                            \
  { const char* abase = lds8 + (bufi)*32768 + (wr >> 1)*16384;                 \
    _Pragma("unroll")                                                          \
    for (int mi = 0; mi < 4; ++mi) {                                           \
      int rl = ((wr & 1) * 64) + mi * 16 + r15;                                \
      afr[mi][0] = LD8(abase, rl, g);                                          \
      afr[mi][1] = LD8(abase, rl, 4 + g);                                      \
    } }

#define ORD_B(bufi, NIBASE, DST)                                               \
  { const char* bbase = lds8 + 65536 + (bufi)*16384;                           \
    _Pragma("unroll")                                                          \
    for (int ni = 0; ni < 2; ++ni) {                                           \
      int rl = wc * 64 + ((NIBASE) + ni) * 16 + r15;                           \
      DST[ni][0] = LD8(bbase, rl, g);                                          \
      DST[ni][1] = LD8(bbase, rl, 4 + g);                                      \
    } }

#define OMFMA(NIBASE, BREG)                                                    \
  { __builtin_amdgcn_s_setprio(1);                                             \
    _Pragma("unroll")                                                          \
    for (int mi = 0; mi < 4; ++mi)                                             \
      _Pragma("unroll")                                                        \
      for (int ni = 0; ni < 2; ++ni)                                           \
        _Pragma("unroll")                                                      \
        for (int ks = 0; ks < 2; ++ks)                                         \
          acc[mi][(NIBASE)+ni] =                                               \
            __builtin_amdgcn_mfma_f32_16x16x32_bf16(afr[mi][ks], BREG[ni][ks], \
                                                    acc[mi][(NIBASE)+ni], 0, 0, 0); \
    __builtin_amdgcn_s_setprio(0); }

__global__ __launch_bounds__(512, 2) void gemm_o256(const unsigned short* __restrict__ Ab,
                                                    const unsigned short* __restrict__ Bbp,
                                                    float* __restrict__ C) {
  __shared__ char lds8[98304];
  int t = threadIdx.x;
  int r15 = t & 15, g = (t & 63) >> 4, w = t >> 6;
  int wr = w >> 1, wc = w & 1;
  int bm = blockIdx.y * 256, bn = blockIdx.x * 128;

  f32x4 acc[4][4] = {};
  bf16x8 afr[4][2], b0r[2][2], b1r[2][2];

  OST_A(0, 0, 0); OST_A(0, 1, 0); OST_B(0, 0);
  OST_A(1, 0, 1); OST_A(1, 1, 1);
  asm volatile("s_waitcnt vmcnt(4)" ::: "memory");
  BAR();

  for (int i = 0; i < 15; ++i) {
    int to = 2 * i + 1, te2 = 2 * i + 2, to2 = 2 * i + 3;
    ORD_A(0); ORD_B(0, 0, b0r);
    OST_B(1, to);
    BAR(); OMFMA(0, b0r); BAR();
    ORD_B(0, 2, b1r);
    OST_A(0, 0, te2);
    BAR(); OMFMA(2, b1r);
    asm volatile("s_waitcnt vmcnt(2)" ::: "memory");
    BAR();
    ORD_A(1); ORD_B(1, 0, b0r);
    OST_A(0, 1, te2); OST_B(0, te2);
    BAR(); OMFMA(0, b0r); BAR();
    ORD_B(1, 2, b1r);
    OST_A(1, 0, to2); OST_A(1, 1, to2);
    BAR(); OMFMA(2, b1r);
    asm volatile("s_waitcnt vmcnt(4)" ::: "memory");
    BAR();
  }
  ORD_A(0); ORD_B(0, 0, b0r);
  OST_B(1, 31);
  BAR(); OMFMA(0, b0r); BAR();
  ORD_B(0, 2, b1r);
  BAR(); OMFMA(2, b1r);
  asm volatile("s_waitcnt vmcnt(0)" ::: "memory");
  BAR();
  ORD_A(1); ORD_B(1, 0, b0r);
  BAR(); OMFMA(0, b0r); BAR();
  ORD_B(1, 2, b1r);
  BAR(); OMFMA(2, b1r);

#pragma unroll
  for (int mi = 0; mi < 4; ++mi) {
    size_t row = (size_t)bm + wr * 64 + mi * 16 + g * 4;
#pragma unroll
    for (int ni = 0; ni < 4; ++ni) {
      int col = bn + wc * 64 + ni * 16 + r15;
#pragma unroll
      for (int r = 0; r < 4; ++r)
        C[(row + r) * O_N + col] = acc[mi][ni][r];
    }
  }
}

// ---------------------------------------------------------------------------
// bf16 MFMA flash attention v10 (unchanged from r21 — 89.6 us best).
// ---------------------------------------------------------------------------
__global__ __launch_bounds__(256, 2) void attn_mfma(const unsigned short* __restrict__ qb,
                                                    const float* __restrict__ gateb,
                                                    const unsigned short* __restrict__ kb,
                                                    const unsigned short* __restrict__ vt,
                                                    unsigned short* __restrict__ obuf) {
  __shared__ unsigned short Ks[2][64 * 128];   // [kv][d], chunk^=(kv&7) swizzle
  __shared__ unsigned short Vt[2][128 * 64];   // [d][sig(tok)], chunk^=(d&7) swizzle
  char* ldsK0 = (char*)Ks;
  char* ldsV0 = (char*)Vt;

  int t = threadIdx.x;
  int l = t & 63, w = t >> 6;
  int c15 = l & 15, g = l >> 4;
  int bid = blockIdx.x;
  int swz = (bid & 7) * 64 + (bid >> 3);
  int qt = swz & 15, h = (swz >> 4) & 15, b = swz >> 8;
  int kh = h >> 2;                          // G = 4
  size_t rowQ0 = (size_t)b * SS + (size_t)qt * 128;
  size_t rowKbase = (size_t)b * SS;

  bf16x8 qf[2][4];
#pragma unroll
  for (int qi = 0; qi < 2; ++qi)
#pragma unroll
    for (int ks = 0; ks < 4; ++ks)
      qf[qi][ks] = *(const bf16x8*)(qb + (rowQ0 + w * 32 + qi * 16 + c15) * O_N
                                       + h * HDD + g * 8 + ks * 32);

  f32x4 accO[2][8] = {};
  float mrun[2] = {-INFINITY, -INFINITY};
  float lrun[2] = {0.f, 0.f};

#define ISSUE_K(bufi, kt_)                                                     \
  {                                                                            \
    size_t rowK0 = rowKbase + (size_t)(kt_) * 64;                              \
    _Pragma("unroll")                                                          \
    for (int it = 0; it < 4; ++it) {                                           \
      int f = it * 256 + t;                                                    \
      int kv = f >> 4;                                                         \
      int schunk = (f & 15) ^ (kv & 7);                                        \
      unsigned ldsbase = (unsigned)((it * 256 + (w << 6)) << 4);               \
      __builtin_amdgcn_global_load_lds(                                        \
          (const unsigned int*)(kb + (rowK0 + kv) * KV_N + kh * HDD + schunk * 8), \
          (unsigned int*)(ldsK0 + (bufi) * 16384 + ldsbase), 16, 0, 0);        \
    }                                                                          \
  }
#define ISSUE_VT(bufi, kt_)                                                    \
  {                                                                            \
    size_t tokbase = rowKbase + (size_t)(kt_) * 64;                            \
    _Pragma("unroll")                                                          \
    for (int it = 0; it < 4; ++it) {                                           \
      int f = it * 256 + t;                                                    \
      int row = f >> 3;                                                        \
      int schunk = (f & 7) ^ (row & 7);                                        \
      unsigned ldsbase = (unsigned)((it * 256 + (w << 6)) << 4);               \
      __builtin_amdgcn_global_load_lds(                                        \
          (const unsigned int*)(vt + (size_t)(kh * 128 + row) * MROWS + tokbase + schunk * 8), \
          (unsigned int*)(ldsV0 + (bufi) * 16384 + ldsbase), 16, 0, 0);        \
    }                                                                          \
  }

  ISSUE_K(0, 0);
  ISSUE_VT(0, 0);
  asm volatile("s_waitcnt vmcnt(0)" ::: "memory");
  __syncthreads();

  const int NT = SS / 64;
  for (int kt = 0; kt < NT; ++kt) {
    int cur = kt & 1, nxt = cur ^ 1;
    char* ldsK = ldsK0 + cur * 16384;
    char* ldsV = ldsV0 + cur * 16384;

    if (kt + 1 < NT) {
      ISSUE_K(nxt, kt + 1);
      ISSUE_VT(nxt, kt + 1);
    }

    f32x4 accS[2][4] = {};
    __builtin_amdgcn_s_setprio(1);
#pragma unroll
    for (int nf = 0; nf < 4; ++nf) {
      int kvr = nf * 16 + c15;
#pragma unroll
      for (int ks = 0; ks < 4; ++ks) {
        bf16x8 kf = *(const bf16x8*)(ldsK + kvr * 256 + ((((g + 4 * ks) ^ (kvr & 7)) << 4)));
#pragma unroll
        for (int qi = 0; qi < 2; ++qi)
          accS[qi][nf] = __builtin_amdgcn_mfma_f32_16x16x32_bf16(kf, qf[qi][ks], accS[qi][nf], 0, 0, 0);
      }
    }
    __builtin_amdgcn_s_setprio(0);

    float mt[2];
#pragma unroll
    for (int qi = 0; qi < 2; ++qi) {
      float m0 = fmaxf(fmaxf(accS[qi][0][0], accS[qi][0][1]), fmaxf(accS[qi][0][2], accS[qi][0][3]));
#pragma unroll
      for (int nf = 1; nf < 4; ++nf)
        m0 = fmaxf(m0, fmaxf(fmaxf(accS[qi][nf][0], accS[qi][nf][1]), fmaxf(accS[qi][nf][2], accS[qi][nf][3])));
      m0 = fmaxf(m0, __shfl_xor(m0, 16, 64));
      m0 = fmaxf(m0, __shfl_xor(m0, 32, 64));
      mt[qi] = m0;
    }

    // defer-max (exp2 space): skip rescale when bounded by 2^THR2 = e^8
    bool safe = (mt[0] <= mrun[0] + THR2_) && (mt[1] <= mrun[1] + THR2_);
    if (!__all(safe)) {
#pragma unroll
      for (int qi = 0; qi < 2; ++qi) {
        float mnew = fmaxf(mrun[qi], mt[qi]);
        float al = fexp2(mrun[qi] - mnew);    // first tile: exp2(-inf)=0
        mrun[qi] = mnew;
        lrun[qi] *= al;
        float alr[4];
#pragma unroll
        for (int r = 0; r < 4; ++r) alr[r] = __shfl(al, g * 4 + r, 16);
#pragma unroll
        for (int df = 0; df < 8; ++df)
#pragma unroll
          for (int r = 0; r < 4; ++r) accO[qi][df][r] *= alr[r];
      }
    }

    u16x8 pfr[2][2];
#pragma unroll
    for (int qi = 0; qi < 2; ++qi) {
      float ps = 0.f;
#pragma unroll
      for (int nf = 0; nf < 4; ++nf) {
        float p0 = fexp2(accS[qi][nf][0] - mrun[qi]);
        float p1 = fexp2(accS[qi][nf][1] - mrun[qi]);
        float p2 = fexp2(accS[qi][nf][2] - mrun[qi]);
        float p3 = fexp2(accS[qi][nf][3] - mrun[qi]);
        ps += (p0 + p1) + (p2 + p3);
        pfr[qi][nf >> 1][(nf & 1) * 4 + 0] = f2bf(p0);
        pfr[qi][nf >> 1][(nf & 1) * 4 + 1] = f2bf(p1);
        pfr[qi][nf >> 1][(nf & 1) * 4 + 2] = f2bf(p2);
        pfr[qi][nf >> 1][(nf & 1) * 4 + 3] = f2bf(p3);
      }
      lrun[qi] += ps;               // per-lane partial; cross-lane in epilogue
    }

    // O += P V : 32 MFMA.  A = pfr (own regs), B = ONE b128 from sigma-space Vt
    __builtin_amdgcn_s_setprio(1);
#pragma unroll
    for (int ks2 = 0; ks2 < 2; ++ks2) {
      bf16x8 pf0 = __builtin_bit_cast(bf16x8, pfr[0][ks2]);
      bf16x8 pf1 = __builtin_bit_cast(bf16x8, pfr[1][ks2]);
#pragma unroll
      for (int df = 0; df < 8; ++df) {
        int d = df * 16 + c15;
        bf16x8 vf = *(const bf16x8*)(ldsV + d * 128 + ((((g + 4 * ks2) ^ (d & 7)) << 4)));
        accO[0][df] = __builtin_amdgcn_mfma_f32_16x16x32_bf16(pf0, vf, accO[0][df], 0, 0, 0);
        accO[1][df] = __builtin_amdgcn_mfma_f32_16x16x32_bf16(pf1, vf, accO[1][df], 0, 0, 0);
      }
    }
    __builtin_amdgcn_s_setprio(0);

    if (kt + 1 < NT) {
      asm volatile("s_waitcnt vmcnt(0)" ::: "memory");
    }
    __syncthreads();
  }

  // epilogue: finish lrun reduce, normalize, sigmoid-gate, bf16 store
#pragma unroll
  for (int qi = 0; qi < 2; ++qi) {
    lrun[qi] += __shfl_xor(lrun[qi], 16, 64);
    lrun[qi] += __shfl_xor(lrun[qi], 32, 64);
    float invL = 1.f / lrun[qi];
    float ivr[4];
#pragma unroll
    for (int r = 0; r < 4; ++r) ivr[r] = __shfl(invL, g * 4 + r, 16);
#pragma unroll
    for (int r = 0; r < 4; ++r) {
      size_t row = rowQ0 + w * 32 + qi * 16 + g * 4 + r;
#pragma unroll
      for (int df = 0; df < 8; ++df) {
        int d = df * 16 + c15;
        float gt = gateb[row * (size_t)O_N + h * HDD + d];
        float sg = 1.f / (1.f + __expf(-gt));
        obuf[row * (size_t)O_N + h * HDD + d] = f2bf(accO[qi][df][r] * ivr[r] * sg);
      }
    }
  }
#undef ISSUE_K
#undef ISSUE_VT
}

// ---------------------------------------------------------------------------
// Launch
// ---------------------------------------------------------------------------
extern "C" void kernel_launch(void* const* d_in, const int* in_sizes, int n_in,
                              void* d_out, int out_size, void* d_ws, size_t ws_size,
                              hipStream_t stream) {
  const float* hs = (const float*)d_in[0];
  // d_in[1] = position_ids (unused by the reference)
  const float* Wq = (const float*)d_in[2];
  const float* Wk = (const float*)d_in[3];
  const float* Wv = (const float*)d_in[4];
  const float* Wo = (const float*)d_in[5];
  const float* nw = (const float*)d_in[6];
  float* out = (float*)d_out;

  // workspace (~121 MB): gate fp32 | bf16: qb,kb,vt,x,ob | bf16 W (contiguous)
  float* gateb = (float*)d_ws;
  unsigned short* qb16 = (unsigned short*)(gateb + (size_t)MROWS * O_N);
  unsigned short* kb16 = qb16 + (size_t)MROWS * O_N;
  unsigned short* vt16 = kb16 + (size_t)MROWS * KV_N;   // V^T [512][4096], sigma-permuted
  unsigned short* xb   = vt16 + (size_t)KV_N * MROWS;
  unsigned short* ob   = xb   + (size_t)MROWS * HIDD;
  unsigned short* wqb  = ob   + (size_t)MROWS * O_N;
  unsigned short* wkb  = wqb  + (size_t)QG_N * KDIM;
  unsigned short* wvb  = wkb  + (size_t)KV_N * KDIM;
  unsigned short* wob  = wvb  + (size_t)KV_N * KDIM;

  // fused weight-convert + RMSNorm (grid-split single dispatch)
  prep_k<<<dim3(NWBLK + MROWS), 256, 0, stream>>>(Wq, Wk, Wv, Wo, hs, nw, wqb, xb);

  gemm_qg256<<<dim3(QG_N/256, MROWS/256), 512, 0, stream>>>(xb, wqb, qb16, gateb);
  gemm_kv<<<dim3(8, MROWS/128), 256, 0, stream>>>(xb, wkb, wvb, kb16, vt16);
  attn_mfma<<<dim3(512), 256, 0, stream>>>(qb16, gateb, kb16, vt16, ob);
  gemm_o256<<<dim3(O_N/128, MROWS/256), 512, 0, stream>>>(ob, wob, out);
}